// Round 7
// baseline (778.128 us; speedup 1.0000x reference)
//
#include <hip/hip_runtime.h>
#include <math.h>

#define B_ 8
#define C_ 128
#define O3_ 384
#define H_ 128
#define W_ 128
#define L_ 16384
#define NS_ 64
#define MAXP_ 2304

typedef float f32x4 __attribute__((ext_vector_type(4)));
typedef short bf16x8 __attribute__((ext_vector_type(8)));

static __device__ __forceinline__ ushort f2bf(float f) {
    uint u = __float_as_uint(f);
    u += 0x7fffu + ((u >> 16) & 1u);
    return (ushort)(u >> 16);
}
static __device__ __forceinline__ float bf2f(ushort h) {
    return __uint_as_float(((uint)h) << 16);
}

// ---------------------------------------------------------------------------
// Weight pre-split: fp32 -> hi/lo bf16 planes (4 weights in one launch)
// ---------------------------------------------------------------------------
__global__ __launch_bounds__(256) void wsplit_k(
    const float* __restrict__ wa, const float* __restrict__ wb,
    const float* __restrict__ wc, const float* __restrict__ wd,
    short* __restrict__ ha, short* __restrict__ la,
    short* __restrict__ hb, short* __restrict__ lb,
    short* __restrict__ hc, short* __restrict__ lc,
    short* __restrict__ hd, short* __restrict__ ld)
{
    const int sel = blockIdx.y;
    const float* w = sel == 0 ? wa : (sel == 1 ? wb : (sel == 2 ? wc : wd));
    short* ph = sel == 0 ? ha : (sel == 1 ? hb : (sel == 2 ? hc : hd));
    short* pl = sel == 0 ? la : (sel == 1 ? lb : (sel == 2 ? lc : ld));
    const int n = sel == 0 ? 49152 : (sel == 1 ? 16384 : 8192);
    const int i = blockIdx.x * 256 + threadIdx.x;
    if (i < n) {
        float v = w[i];
        ushort h = f2bf(v);
        ph[i] = (short)h;
        pl[i] = (short)f2bf(v - bf2f(h));
    }
}

__global__ __launch_bounds__(256) void wsplit1_k(const float* __restrict__ w,
    short* __restrict__ ph, short* __restrict__ pl, int n)
{
    const int i = blockIdx.x * 256 + threadIdx.x;
    if (i < n) {
        float v = w[i];
        ushort h = f2bf(v);
        ph[i] = (short)h;
        pl[i] = (short)f2bf(v - bf2f(h));
    }
}

// ---------------------------------------------------------------------------
// Transpose+split: x [b][128c][L] fp32 -> xThi/xTlo [b][L][128c] bf16 planes
// ---------------------------------------------------------------------------
__global__ __launch_bounds__(256) void transp_k(const float* __restrict__ x,
    short* __restrict__ xhi, short* __restrict__ xlo)
{
    __shared__ float t[128][33];
    const int b = blockIdx.y;
    const int l0 = blockIdx.x * 32;
    const int tid = threadIdx.x;
    {
        const int c = tid >> 1, half = tid & 1;
        const float* src = x + ((size_t)b * C_ + c) * L_ + l0 + half * 16;
#pragma unroll
        for (int u = 0; u < 4; u++) {
            float4 v = *reinterpret_cast<const float4*>(src + u * 4);
            t[c][half * 16 + u * 4 + 0] = v.x;
            t[c][half * 16 + u * 4 + 1] = v.y;
            t[c][half * 16 + u * 4 + 2] = v.z;
            t[c][half * 16 + u * 4 + 3] = v.w;
        }
    }
    __syncthreads();
    {
        const int l = tid >> 3, strip = tid & 7;
        uint hi[8], lo[8];
#pragma unroll
        for (int i = 0; i < 8; i++) {
            float a0 = t[strip * 16 + 2 * i][l], a1 = t[strip * 16 + 2 * i + 1][l];
            ushort h0 = f2bf(a0), h1 = f2bf(a1);
            ushort g0 = f2bf(a0 - bf2f(h0)), g1 = f2bf(a1 - bf2f(h1));
            hi[i] = (uint)h0 | ((uint)h1 << 16);
            lo[i] = (uint)g0 | ((uint)g1 << 16);
        }
        size_t ob = ((size_t)b * L_ + l0 + l) * C_ + strip * 16;
        uint4* ph = reinterpret_cast<uint4*>(xhi + ob);
        uint4* pl = reinterpret_cast<uint4*>(xlo + ob);
        ph[0] = *reinterpret_cast<uint4*>(&hi[0]);
        ph[1] = *reinterpret_cast<uint4*>(&hi[4]);
        pl[0] = *reinterpret_cast<uint4*>(&lo[0]);
        pl[1] = *reinterpret_cast<uint4*>(&lo[4]);
    }
}

// ---------------------------------------------------------------------------
// Barrier-free LDS-free NT MFMA GEMM (bf16x3).
// A pre-split hi/lo planes [b][L][KD]; W pre-split [ON][KD] (L2-resident).
// Block = LW*64 l-rows x ON o (full o). Wave (wr,wc): 64 l x 64 o, acc[4][4].
// MODE 1: y=gelu(acc+bias)*(sxy at yi) -> split [l][o]
// MODE 2: y=acc+bias -> split [l][o]
// MODE 3: y=acc+bias+E0 -> split [l][o]
// MODE 4: plain, fp32 transposed store [o][l]
// ---------------------------------------------------------------------------
template<int KD, int ON, int MODE, int LW>
__global__ __launch_bounds__(LW*(ON/64)*64) void mgemm_k(
    const short* __restrict__ Whi, const short* __restrict__ Wlo,
    const float* __restrict__ bias,
    const short* __restrict__ Ahi, const short* __restrict__ Alo,
    const float* __restrict__ E0,
    float* __restrict__ Yf, short* __restrict__ Yhi, short* __restrict__ Ylo)
{
    constexpr int WO = ON / 64;
    constexpr int T = KD / 32;
    const int tid = threadIdx.x;
    const int lane = tid & 63;
    const int wid = tid >> 6;
    const int wr = wid / WO, wc = wid % WO;
    const int b = blockIdx.y;
    const int lB = blockIdx.x * (LW * 64) + wr * 64;
    const int ln15 = lane & 15, lg = lane >> 4;

    const size_t arow0 = ((size_t)b * L_ + lB + ln15) * KD + lg * 8;
    const size_t brow0 = (size_t)(wc * 64 + ln15) * KD + lg * 8;

    f32x4 acc[4][4];
#pragma unroll
    for (int m = 0; m < 4; m++)
#pragma unroll
        for (int n = 0; n < 4; n++)
#pragma unroll
            for (int r = 0; r < 4; r++) acc[m][n][r] = 0.f;

    bf16x8 A0h[4], A0l[4], A1h[4], A1l[4];

    auto ldA = [&](bf16x8* Ah, bf16x8* Al, int t) {
#pragma unroll
        for (int m = 0; m < 4; m++) {
            size_t g = arow0 + (size_t)(m * 16) * KD + t * 32;
            Ah[m] = *reinterpret_cast<const bf16x8*>(Ahi + g);
            Al[m] = *reinterpret_cast<const bf16x8*>(Alo + g);
        }
    };
    auto comp = [&](const bf16x8* Ah, const bf16x8* Al, int t) {
#pragma unroll
        for (int n = 0; n < 4; n++) {
            size_t g = brow0 + (size_t)(n * 16) * KD + t * 32;
            bf16x8 Bh = *reinterpret_cast<const bf16x8*>(Whi + g);
            bf16x8 Bl = *reinterpret_cast<const bf16x8*>(Wlo + g);
#pragma unroll
            for (int m = 0; m < 4; m++) {
                acc[m][n] = __builtin_amdgcn_mfma_f32_16x16x32_bf16(Ah[m], Bh, acc[m][n], 0, 0, 0);
                acc[m][n] = __builtin_amdgcn_mfma_f32_16x16x32_bf16(Ah[m], Bl, acc[m][n], 0, 0, 0);
                acc[m][n] = __builtin_amdgcn_mfma_f32_16x16x32_bf16(Al[m], Bh, acc[m][n], 0, 0, 0);
            }
        }
    };

    ldA(A0h, A0l, 0);
#pragma unroll
    for (int t = 0; t < T; t += 2) {
        if (t + 1 < T) ldA(A1h, A1l, t + 1);
        comp(A0h, A0l, t);
        if (t + 2 < T) ldA(A0h, A0l, t + 2);
        comp(A1h, A1l, t + 1);
    }

#pragma unroll
    for (int m = 0; m < 4; m++) {
        const int l = lB + m * 16 + lg * 4;
#pragma unroll
        for (int n = 0; n < 4; n++) {
            const int o = wc * 64 + n * 16 + ln15;
            if constexpr (MODE == 4) {
                float4 r4 = {acc[m][n][0], acc[m][n][1], acc[m][n][2], acc[m][n][3]};
                *reinterpret_cast<float4*>(&Yf[((size_t)b * ON + o) * L_ + l]) = r4;
            } else {
                float bv = bias[o];
#pragma unroll
                for (int r = 0; r < 4; r++) {
                    size_t yi = ((size_t)b * L_ + l + r) * ON + o;
                    float a = acc[m][n][r] + bv;
                    if constexpr (MODE == 1) {
                        float sxy = bf2f((ushort)Ahi[yi]) + bf2f((ushort)Alo[yi]);
                        a = 0.5f * a * (1.f + erff(a * 0.70710678118654752f)) * sxy;
                    }
                    if constexpr (MODE == 3) a += E0[yi];
                    ushort h = f2bf(a);
                    ushort g = f2bf(a - bf2f(h));
                    Yhi[yi] = (short)h;
                    Ylo[yi] = (short)g;
                }
            }
        }
    }
}

// ---------------------------------------------------------------------------
// Depthwise 3x3 SAME conv, register-rolling, shfl halos, fused q/k sums
// ---------------------------------------------------------------------------
__global__ __launch_bounds__(256) void dwconv_k(const float* __restrict__ in,
    const float* __restrict__ wdw, float* __restrict__ outp,
    float* __restrict__ sumq, float* __restrict__ sumk,
    float* __restrict__ ssq, float* __restrict__ ssk)
{
    const int ch = blockIdx.x, b = blockIdx.y;
    const int tid = threadIdx.x;
    const int tx = tid & 31, band = tid >> 5;
    const int x0 = tx * 4;
    const int y0 = band * 16;
    const size_t base = ((size_t)b * O3_ + ch) * L_;
    const float* wp = wdw + ch * 9;
    float w0 = wp[0], w1 = wp[1], w2 = wp[2], w3 = wp[3], w4 = wp[4],
          w5 = wp[5], w6 = wp[6], w7 = wp[7], w8 = wp[8];

    float s1 = 0.f, s2 = 0.f;
    float b0[6], b1[6], b2[6];

    auto loadrow = [&](int gy, float* r) {
        float4 m = {0.f, 0.f, 0.f, 0.f};
        if ((unsigned)gy < (unsigned)H_)
            m = *reinterpret_cast<const float4*>(in + base + (size_t)gy * W_ + x0);
        float left  = __shfl_up(m.w, 1, 32);
        float right = __shfl_down(m.x, 1, 32);
        r[0] = (tx == 0) ? 0.f : left;
        r[1] = m.x; r[2] = m.y; r[3] = m.z; r[4] = m.w;
        r[5] = (tx == 31) ? 0.f : right;
    };
    auto conv3 = [&](const float* ra, const float* rb, const float* rc, int yy) {
        float o0 = ra[0]*w0 + ra[1]*w1 + ra[2]*w2 + rb[0]*w3 + rb[1]*w4 + rb[2]*w5 + rc[0]*w6 + rc[1]*w7 + rc[2]*w8;
        float o1 = ra[1]*w0 + ra[2]*w1 + ra[3]*w2 + rb[1]*w3 + rb[2]*w4 + rb[3]*w5 + rc[1]*w6 + rc[2]*w7 + rc[3]*w8;
        float o2 = ra[2]*w0 + ra[3]*w1 + ra[4]*w2 + rb[2]*w3 + rb[3]*w4 + rb[4]*w5 + rc[2]*w6 + rc[3]*w7 + rc[4]*w8;
        float o3 = ra[3]*w0 + ra[4]*w1 + ra[5]*w2 + rb[3]*w3 + rb[4]*w4 + rb[5]*w5 + rc[3]*w6 + rc[4]*w7 + rc[5]*w8;
        float4 o4 = {o0, o1, o2, o3};
        *reinterpret_cast<float4*>(&outp[base + (size_t)(y0 + yy) * W_ + x0]) = o4;
        s1 += (o0 + o1) + (o2 + o3);
        s2 += o0*o0 + o1*o1 + o2*o2 + o3*o3;
    };

    loadrow(y0 - 1, b0);
    loadrow(y0,     b1);
#pragma unroll
    for (int y3 = 0; y3 < 15; y3 += 3) {
        loadrow(y0 + y3 + 1, b2); conv3(b0, b1, b2, y3);
        loadrow(y0 + y3 + 2, b0); conv3(b1, b2, b0, y3 + 1);
        loadrow(y0 + y3 + 3, b1); conv3(b2, b0, b1, y3 + 2);
    }
    loadrow(y0 + 16, b2); conv3(b0, b1, b2, 15);

    __shared__ float r1[256], r2[256];
    if (ch < 256) {
        r1[tid] = s1; r2[tid] = s2;
        __syncthreads();
        for (int st = 128; st > 0; st >>= 1) {
            if (tid < st) { r1[tid] += r1[tid + st]; r2[tid] += r2[tid + st]; }
            __syncthreads();
        }
        if (tid == 0) {
            if (ch < 128) { sumq[b * 128 + ch] = r1[0]; ssq[b * 128 + ch] = r2[0]; }
            else          { sumk[b * 128 + ch - 128] = r1[0]; ssk[b * 128 + ch - 128] = r2[0]; }
        }
    }
}

// combine: channel means (double) -> stable rank; rq,rk; gm
__global__ void combine_k(const float* __restrict__ sumq, const float* __restrict__ sumk,
    const float* __restrict__ ssq, const float* __restrict__ ssk,
    int* __restrict__ idxp, float* __restrict__ rqc, float* __restrict__ rkc,
    float* __restrict__ gm)
{
    const int t = threadIdx.x; // 128
    __shared__ double cms[128];
    double s = 0.0;
    for (int b = 0; b < B_; b++) s += (double)sumq[b * 128 + t];
    cms[t] = s;
    float rqv[B_], rkv[B_];
    for (int b = 0; b < B_; b++) {
        rqv[b] = 1.f / fmaxf(sqrtf(ssq[b * 128 + t]), 1e-12f);
        rkv[b] = 1.f / fmaxf(sqrtf(ssk[b * 128 + t]), 1e-12f);
        rqc[b * 128 + t] = rqv[b];
        rkc[b * 128 + t] = rkv[b];
    }
    __syncthreads();
    const double mv = cms[t];
    int r = 0;
    for (int j = 0; j < 128; j++) {
        double o = cms[j];
        if (o > mv || (o == mv && j < t)) r++;
    }
    idxp[r] = t;
    for (int b = 0; b < B_; b++)
        gm[b * 128 + r] = (rqv[b] * sumq[b * 128 + t] + rkv[b] * sumk[b * 128 + t]) * (1.0f / L_);
}

// ---------------------------------------------------------------------------
// Partial raw scores: S[c][d] = sum_l q[c,l]*k[d,l] over one L-split (per-G)
// ---------------------------------------------------------------------------
template<int G>
__global__ __launch_bounds__(256) void score_k(const float* __restrict__ dw, const int* __restrict__ idxp,
    int start, int gi, float* __restrict__ spart)
{
    constexpr int TS = G / 16;
    const int split = blockIdx.x, b = blockIdx.y;
    const int tid = threadIdx.x, tx = tid & 15, ty = tid >> 4;
    __shared__ float sQ[G][66];
    __shared__ float sK[G][66];
    __shared__ int sc[G];
    if (tid < G) sc[tid] = idxp[start + tid];
    __syncthreads();

    float acc[TS][TS];
#pragma unroll
    for (int i = 0; i < TS; i++)
#pragma unroll
        for (int j = 0; j < TS; j++) acc[i][j] = 0.f;

    const int l0 = split * (L_ / NS_);
    constexpr int LPT = (G * 64) / 256;
    for (int chk = 0; chk < L_ / NS_; chk += 64) {
#pragma unroll
        for (int i = 0; i < LPT; i++) {
            int id = tid + i * 256;
            int row = id >> 6, lc = id & 63;
            size_t base = ((size_t)b * O3_ + sc[row]) * L_ + l0 + chk + lc;
            sQ[row][lc] = dw[base];
            sK[row][lc] = dw[base + (size_t)128 * L_];
        }
        __syncthreads();
#pragma unroll
        for (int kk = 0; kk < 64; kk++) {
            float qv[TS], kv[TS];
#pragma unroll
            for (int j = 0; j < TS; j++) { qv[j] = sQ[ty * TS + j][kk]; kv[j] = sK[tx * TS + j][kk]; }
#pragma unroll
            for (int i = 0; i < TS; i++)
#pragma unroll
                for (int j = 0; j < TS; j++)
                    acc[i][j] = fmaf(qv[i], kv[j], acc[i][j]);
        }
        __syncthreads();
    }
    float* op = spart + (((size_t)(b * 4 + gi)) * NS_ + split) * MAXP_;
#pragma unroll
    for (int i = 0; i < TS; i++)
#pragma unroll
        for (int j = 0; j < TS; j++)
            op[(ty * TS + i) * G + tx * TS + j] = acc[i][j];
}

// reduce partials, scale by rq*rk*temp, softmax rows -> attn
__global__ __launch_bounds__(256) void softmax_k(const float* __restrict__ spart,
    const float* __restrict__ rqc, const float* __restrict__ rkc, const int* __restrict__ idxp,
    const float* __restrict__ temp, float* __restrict__ attn)
{
    const int gi = blockIdx.x, b = blockIdx.y;
    const int g = (gi == 0) ? 16 : (gi == 3 ? 48 : 32);
    const int start = (gi == 0) ? 0 : (gi == 1 ? 16 : (gi == 2 ? 48 : 80));
    __shared__ float S[MAXP_];
    __shared__ int sidx[48];
    if (threadIdx.x < g) sidx[threadIdx.x] = idxp[start + threadIdx.x];
    __syncthreads();
    const float tv = temp[gi];
    for (int p = threadIdx.x; p < g * g; p += 256) {
        float s = 0.f;
        const float* sp = spart + ((size_t)(b * 4 + gi)) * NS_ * MAXP_ + p;
        for (int k = 0; k < NS_; k++) s += sp[(size_t)k * MAXP_];
        int cc = p / g, dd = p - cc * g;
        S[p] = s * rqc[b * 128 + sidx[cc]] * rkc[b * 128 + sidx[dd]] * tv;
    }
    __syncthreads();
    const int wv = threadIdx.x >> 6, lane = threadIdx.x & 63;
    for (int r = wv; r < g; r += 4) {
        float val = (lane < g) ? S[r * g + lane] : -1e30f;
        float mx = val;
        for (int m = 32; m > 0; m >>= 1) mx = fmaxf(mx, __shfl_xor(mx, m));
        float e = (lane < g) ? expf(val - mx) : 0.f;
        float sum = e;
        for (int m = 32; m > 0; m >>= 1) sum += __shfl_xor(sum, m);
        if (lane < g) attn[((size_t)(b * 4 + gi)) * MAXP_ + r * g + lane] = e / sum;
    }
}

// ---------------------------------------------------------------------------
// attn @ v per-G: outallT fp32 [b][l][c]; sxy split hi/lo planes.
// ---------------------------------------------------------------------------
template<int G>
__global__ __launch_bounds__(256) void av3_k(const float* __restrict__ dw, const int* __restrict__ idxp,
    const float* __restrict__ rqc, const float* __restrict__ rkc,
    const float* __restrict__ attn, int start, int gi,
    float* __restrict__ outallT, short* __restrict__ sxyhi, short* __restrict__ sxylo)
{
    constexpr int C4 = G / 4;
    constexpr int GP = G + 1;
    const int b = blockIdx.y;
    const int lB = blockIdx.x * 64;
    const int tid = threadIdx.x;
    __shared__ float sA[G * GP];
    __shared__ float sV[64][GP];
    __shared__ int cv[G];
    __shared__ float rqs[G], rks[G];
    if (tid < G) {
        int c0 = idxp[start + tid];
        cv[tid] = c0;
        rqs[tid] = rqc[b * 128 + c0];
        rks[tid] = rkc[b * 128 + c0];
    }
    for (int p = tid; p < G * G; p += 256) {
        int cc = p / G, dd = p - cc * G;
        sA[cc * GP + dd] = attn[((size_t)(b * 4 + gi)) * MAXP_ + p];
    }
    __syncthreads();
    for (int idx = tid; idx < 64 * G; idx += 256) {
        int l = idx & 63, d = idx >> 6;
        sV[l][d] = dw[((size_t)b * O3_ + 256 + cv[d]) * L_ + lB + l];
    }
    __syncthreads();
    const int strip = tid & 3, l = tid >> 2;
    float acc[C4];
#pragma unroll
    for (int j = 0; j < C4; j++) acc[j] = 0.f;
    for (int d = 0; d < G; d++) {
        float vd = sV[l][d];
#pragma unroll
        for (int j = 0; j < C4; j++)
            acc[j] = fmaf(sA[(strip * C4 + j) * GP + d], vd, acc[j]);
    }
    const size_t ob = ((size_t)b * L_ + lB + l) * C_ + start + strip * C4;
    float sv[C4];
#pragma unroll
    for (int j = 0; j < C4; j++) {
        int c = strip * C4 + j;
        float q = dw[((size_t)b * O3_ + cv[c]) * L_ + lB + l];
        float k = dw[((size_t)b * O3_ + 128 + cv[c]) * L_ + lB + l];
        sv[j] = acc[j] + rqs[c] * q + rks[c] * k;
    }
#pragma unroll
    for (int j = 0; j < C4; j += 4) {
        float4 o4 = {acc[j], acc[j + 1], acc[j + 2], acc[j + 3]};
        *reinterpret_cast<float4*>(&outallT[ob + j]) = o4;
    }
#pragma unroll
    for (int j = 0; j < C4; j += 2) {
        ushort h0 = f2bf(sv[j]), h1 = f2bf(sv[j + 1]);
        ushort g0 = f2bf(sv[j] - bf2f(h0)), g1 = f2bf(sv[j + 1] - bf2f(h1));
        *reinterpret_cast<uint*>(&sxyhi[ob + j]) = (uint)h0 | ((uint)h1 << 16);
        *reinterpret_cast<uint*>(&sxylo[ob + j]) = (uint)g0 | ((uint)g1 << 16);
    }
}

// qv_cache = 0.9 * mean of tiled group means, broadcast over spatial
__global__ __launch_bounds__(256) void qvc_k(const float* __restrict__ gm, float* __restrict__ outq)
{
    const int cpos = blockIdx.x, b = blockIdx.y;
    const float* g = gm + b * 128;
    float v = g[cpos & 15] + g[16 + (cpos & 31)] + g[48 + (cpos & 31)];
    if (cpos < 96) v += g[80 + (cpos % 48)];
    v *= 0.225f; // 0.9 * (sum/4)
    float4 vv = {v, v, v, v};
    float4* op = reinterpret_cast<float4*>(outq + ((size_t)b * C_ + cpos) * L_);
    for (int i = threadIdx.x; i < L_ / 4; i += 256) op[i] = vv;
}

// ---------------------------------------------------------------------------
extern "C" void kernel_launch(void* const* d_in, const int* in_sizes, int n_in,
                              void* d_out, int out_size, void* d_ws, size_t ws_size,
                              hipStream_t stream)
{
    const float* x     = (const float*)d_in[0];
    const float* temp  = (const float*)d_in[1];
    const float* wqkv  = (const float*)d_in[2];
    const float* wdw   = (const float*)d_in[3];
    const float* wproj = (const float*)d_in[4];
    const float* wgate = (const float*)d_in[5];
    const float* bgate = (const float*)d_in[6];
    const float* wdown = (const float*)d_in[7];
    const float* bdown = (const float*)d_in[8];
    const float* wup   = (const float*)d_in[9];
    const float* bup   = (const float*)d_in[10];
    float* out = (float*)d_out;
    float* ws  = (float*)d_ws;

    // --- ws layout ---
    float* qkvCL = ws;                          // [b][384][L] fp32  [0, 50331648)
    float* dwCL  = ws + 50331648ull;            // [b][384][L] fp32  [50331648, 100663296)
    short* xThi  = (short*)(ws + 50331648ull);  // xT planes: dead before dwconv writes
    short* xTlo  = xThi + 16777216ull;
    float* outallT = ws;                        // fp32 [b][L][128]   [0, 16777216)
    short* sxyhi   = (short*)(ws + 16777216ull);
    short* sxylo   = sxyhi + 16777216ull;
    short* gatedhi = (short*)(ws + 33554432ull);
    short* gatedlo = gatedhi + 16777216ull;
    short* mod1hi  = (short*)(ws + 16777216ull);
    short* mod1lo  = mod1hi + 8388608ull;
    short* out2hi  = (short*)(ws + 33554432ull);
    short* out2lo  = out2hi + 16777216ull;
    // wproj planes: created after up, in the then-dead mod1 region tail
    short* wprojh  = (short*)(ws + 25165824ull);
    short* wprojl  = wprojh + 16384ull;

    // --- d_out layout (first half scratch until proj; second half qv_cache) ---
    float* spart = out;                         // [0, 4718592)
    float* attn  = out + 4718592ull;
    float* sumq  = out + 4800000ull;
    float* sumk  = out + 4801024ull;
    float* ssq   = out + 4802048ull;
    float* ssk   = out + 4803072ull;
    float* rqc   = out + 4804096ull;
    float* rkc   = out + 4805120ull;
    float* gm    = out + 4806144ull;
    int*   idxp  = (int*)(out + 4807168ull);
    // weight hi/lo planes (dead region until proj overwrites; consumed before)
    short* wqkvh = (short*)(out + 4900000ull);
    short* wqkvl = (short*)(out + 4924576ull);
    short* wgateh= (short*)(out + 4949152ull);
    short* wgatel= (short*)(out + 4957344ull);
    short* wdownh= (short*)(out + 4965536ull);
    short* wdownl= (short*)(out + 4969632ull);
    short* wuph  = (short*)(out + 4973728ull);
    short* wupl  = (short*)(out + 4977824ull);

    // 0. weight pre-split (qkv, gate, down, up)
    wsplit_k<<<dim3(192, 4), 256, 0, stream>>>(wqkv, wgate, wdown, wup,
        wqkvh, wqkvl, wgateh, wgatel, wdownh, wdownl, wuph, wupl);
    // 1. transpose+split x
    transp_k<<<dim3(512, 8), 256, 0, stream>>>(x, xThi, xTlo);
    // 2. qkv GEMM (LDS-free, full-o blocks) -> qkvCL fp32 [b][384][l]
    mgemm_k<128, 384, 4, 1><<<dim3(256, 8), 384, 0, stream>>>(
        wqkvh, wqkvl, nullptr, xThi, xTlo, nullptr, qkvCL, nullptr, nullptr);
    // 3. depthwise 3x3 + fused q/k sums
    dwconv_k<<<dim3(384, 8), 256, 0, stream>>>(qkvCL, wdw, dwCL, sumq, sumk, ssq, ssk);
    // 4. combine: rank + norms + gm
    combine_k<<<1, 128, 0, stream>>>(sumq, sumk, ssq, ssk, idxp, rqc, rkc, gm);
    // 5. attention scores (per-G launches)
    score_k<16><<<dim3(NS_, 8), 256, 0, stream>>>(dwCL, idxp, 0, 0, spart);
    score_k<32><<<dim3(NS_, 8), 256, 0, stream>>>(dwCL, idxp, 16, 1, spart);
    score_k<32><<<dim3(NS_, 8), 256, 0, stream>>>(dwCL, idxp, 48, 2, spart);
    score_k<48><<<dim3(NS_, 8), 256, 0, stream>>>(dwCL, idxp, 80, 3, spart);
    // 6. reduce + softmax
    softmax_k<<<dim3(4, 8), 256, 0, stream>>>(spart, rqc, rkc, idxp, temp, attn);
    // 7. attn @ v (per-G launches) -> outallT fp32 + sxy hi/lo planes
    av3_k<16><<<dim3(256, 8), 256, 0, stream>>>(dwCL, idxp, rqc, rkc, attn, 0, 0, outallT, sxyhi, sxylo);
    av3_k<32><<<dim3(256, 8), 256, 0, stream>>>(dwCL, idxp, rqc, rkc, attn, 16, 1, outallT, sxyhi, sxylo);
    av3_k<32><<<dim3(256, 8), 256, 0, stream>>>(dwCL, idxp, rqc, rkc, attn, 48, 2, outallT, sxyhi, sxylo);
    av3_k<48><<<dim3(256, 8), 256, 0, stream>>>(dwCL, idxp, rqc, rkc, attn, 80, 3, outallT, sxyhi, sxylo);
    // 8. gate GEMM (+gelu * sxy)
    mgemm_k<128, 128, 1, 2><<<dim3(128, 8), 256, 0, stream>>>(
        wgateh, wgatel, bgate, sxyhi, sxylo, nullptr, nullptr, gatedhi, gatedlo);
    // 9. qv_cache
    qvc_k<<<dim3(128, 8), 256, 0, stream>>>(gm, out + 16777216ull);
    // 10. down GEMM
    mgemm_k<128, 64, 2, 4><<<dim3(64, 8), 256, 0, stream>>>(
        wdownh, wdownl, bdown, gatedhi, gatedlo, nullptr, nullptr, mod1hi, mod1lo);
    // 11. up GEMM + residual
    mgemm_k<64, 128, 3, 2><<<dim3(128, 8), 256, 0, stream>>>(
        wuph, wupl, bup, mod1hi, mod1lo, outallT, nullptr, out2hi, out2lo);
    // 12. wproj pre-split (mod1 region is dead now)
    wsplit1_k<<<64, 256, 0, stream>>>(wproj, wprojh, wprojl, 16384);
    // 13. proj GEMM -> final output fp32 [b][128][l]
    mgemm_k<128, 128, 4, 2><<<dim3(128, 8), 256, 0, stream>>>(
        wprojh, wprojl, nullptr, out2hi, out2lo, nullptr, out, nullptr, nullptr);
}

// Round 10
// 766.165 us; speedup vs baseline: 1.0156x; 1.0156x over previous
//
#include <hip/hip_runtime.h>
#include <math.h>

#define B_ 8
#define C_ 128
#define O3_ 384
#define H_ 128
#define W_ 128
#define L_ 16384
#define NS_ 64
#define MAXP_ 2304

typedef float f32x4 __attribute__((ext_vector_type(4)));
typedef short bf16x8 __attribute__((ext_vector_type(8)));

static __device__ __forceinline__ ushort f2bf(float f) {
    uint u = __float_as_uint(f);
    u += 0x7fffu + ((u >> 16) & 1u);
    return (ushort)(u >> 16);
}
static __device__ __forceinline__ float bf2f(ushort h) {
    return __uint_as_float(((uint)h) << 16);
}

// ---------------------------------------------------------------------------
// Weight pre-split: fp32 -> hi/lo bf16 planes
// ---------------------------------------------------------------------------
__global__ __launch_bounds__(256) void wsplit_k(
    const float* __restrict__ wa, const float* __restrict__ wb,
    const float* __restrict__ wc, const float* __restrict__ wd,
    short* __restrict__ ha, short* __restrict__ la,
    short* __restrict__ hb, short* __restrict__ lb,
    short* __restrict__ hc, short* __restrict__ lc,
    short* __restrict__ hd, short* __restrict__ ld)
{
    const int sel = blockIdx.y;
    const float* w = sel == 0 ? wa : (sel == 1 ? wb : (sel == 2 ? wc : wd));
    short* ph = sel == 0 ? ha : (sel == 1 ? hb : (sel == 2 ? hc : hd));
    short* pl = sel == 0 ? la : (sel == 1 ? lb : (sel == 2 ? lc : ld));
    const int n = sel == 0 ? 49152 : (sel == 1 ? 16384 : 8192);
    const int i = blockIdx.x * 256 + threadIdx.x;
    if (i < n) {
        float v = w[i];
        ushort h = f2bf(v);
        ph[i] = (short)h;
        pl[i] = (short)f2bf(v - bf2f(h));
    }
}

__global__ __launch_bounds__(256) void wsplit1_k(const float* __restrict__ w,
    short* __restrict__ ph, short* __restrict__ pl, int n)
{
    const int i = blockIdx.x * 256 + threadIdx.x;
    if (i < n) {
        float v = w[i];
        ushort h = f2bf(v);
        ph[i] = (short)h;
        pl[i] = (short)f2bf(v - bf2f(h));
    }
}

// ---------------------------------------------------------------------------
// Transpose+split: x [b][128c][L] fp32 -> xThi/xTlo [b][L][128c] bf16 planes
// ---------------------------------------------------------------------------
__global__ __launch_bounds__(256) void transp_k(const float* __restrict__ x,
    short* __restrict__ xhi, short* __restrict__ xlo)
{
    __shared__ float t[128][33];
    const int b = blockIdx.y;
    const int l0 = blockIdx.x * 32;
    const int tid = threadIdx.x;
    {
        const int c = tid >> 1, half = tid & 1;
        const float* src = x + ((size_t)b * C_ + c) * L_ + l0 + half * 16;
#pragma unroll
        for (int u = 0; u < 4; u++) {
            float4 v = *reinterpret_cast<const float4*>(src + u * 4);
            t[c][half * 16 + u * 4 + 0] = v.x;
            t[c][half * 16 + u * 4 + 1] = v.y;
            t[c][half * 16 + u * 4 + 2] = v.z;
            t[c][half * 16 + u * 4 + 3] = v.w;
        }
    }
    __syncthreads();
    {
        const int l = tid >> 3, strip = tid & 7;
        uint hi[8], lo[8];
#pragma unroll
        for (int i = 0; i < 8; i++) {
            float a0 = t[strip * 16 + 2 * i][l], a1 = t[strip * 16 + 2 * i + 1][l];
            ushort h0 = f2bf(a0), h1 = f2bf(a1);
            ushort g0 = f2bf(a0 - bf2f(h0)), g1 = f2bf(a1 - bf2f(h1));
            hi[i] = (uint)h0 | ((uint)h1 << 16);
            lo[i] = (uint)g0 | ((uint)g1 << 16);
        }
        size_t ob = ((size_t)b * L_ + l0 + l) * C_ + strip * 16;
        uint4* ph = reinterpret_cast<uint4*>(xhi + ob);
        uint4* pl = reinterpret_cast<uint4*>(xlo + ob);
        ph[0] = *reinterpret_cast<uint4*>(&hi[0]);
        ph[1] = *reinterpret_cast<uint4*>(&hi[4]);
        pl[0] = *reinterpret_cast<uint4*>(&lo[0]);
        pl[1] = *reinterpret_cast<uint4*>(&lo[4]);
    }
}

// ---------------------------------------------------------------------------
// NT MFMA GEMM (bf16x3). B resident in LDS (staged once, XOR-swizzled);
// A single-buffer, reg-staged split: ldg(t+1) issued before MFMA(t),
// ds_write(t+1) after (vmcnt wait sinks there, latency hides under MFMA).
// MODE 1: y=gelu(acc+bias)*(sxy at yi) -> split [l][o]
// MODE 2: y=acc+bias -> split [l][o]
// MODE 3: y=acc+bias+E0 -> split [l][o]
// MODE 4: plain, fp32 transposed store [o][l]
// ---------------------------------------------------------------------------
template<int KD, int OT, int MODE>
__global__ __launch_bounds__(256) void mgemm_k(
    const short* __restrict__ Whi, const short* __restrict__ Wlo,
    const float* __restrict__ bias,
    const short* __restrict__ Ahi, const short* __restrict__ Alo,
    const float* __restrict__ E0,
    float* __restrict__ Yf, short* __restrict__ Yhi, short* __restrict__ Ylo)
{
    constexpr int WC = OT / 64;           // wave-cols
    constexpr int WR = 4 / WC;            // wave-rows
    constexpr int LT = WR * 64;           // l-tile per block
    constexpr int T  = KD / 32;           // k-steps
    constexpr int ABYTES = LT * 64;       // A bytes/plane per k-step
    constexpr int BBYTES = OT * KD * 2;   // B bytes/plane total
    constexpr int CA = WR;                // A 16B-chunks per thread per plane
    constexpr int CB = (OT * KD) / 2048;  // B 16B-chunks per thread per plane
    __shared__ __align__(16) char sAh[ABYTES];
    __shared__ __align__(16) char sAl[ABYTES];
    __shared__ __align__(16) char sBh[BBYTES];
    __shared__ __align__(16) char sBl[BBYTES];

    const int tid = threadIdx.x;
    const int lane = tid & 63;
    const int wid = tid >> 6;
    const int wr = wid / WC, wc = wid % WC;
    const int oB = blockIdx.x * OT;
    const int lB = blockIdx.y * LT;
    const int ON = gridDim.x * OT;
    const int b  = blockIdx.z;
    const int ln15 = lane & 15, lg = lane >> 4;
    const int m0A = (ln15 >> 1) & 3;          // A read slot xor (lane-const)
    const int m0B = ln15 & 3;                 // B read slot xor
    const int m1B = (ln15 >> 2) & (T - 1);    // B read t xor

    const size_t abase = ((size_t)b * L_ + lB) * KD;

    // B: stage once (ldg + swizzled ds_write)
    {
#pragma unroll
        for (int p = 0; p < CB; p++) {
            const int id = tid + p * 256;
            const int row = id / (KD / 8), cs = id % (KD / 8);
            const int tt = cs >> 2, ks = cs & 3;
            const size_t src = (size_t)(oB + row) * KD + cs * 8;
            const int dst = row * (KD * 2) + ((tt ^ ((row >> 2) & (T - 1))) * 64)
                          + ((ks ^ (row & 3)) << 4);
            *reinterpret_cast<uint4*>(sBh + dst) = *reinterpret_cast<const uint4*>(Whi + src);
            *reinterpret_cast<uint4*>(sBl + dst) = *reinterpret_cast<const uint4*>(Wlo + src);
        }
    }

    uint4 pAh[CA], pAl[CA];
    auto ldgA = [&](int t) {
#pragma unroll
        for (int p = 0; p < CA; p++) {
            const int id = tid + p * 256;
            const int row = id >> 2, s = id & 3;
            const size_t src = abase + (size_t)row * KD + t * 32 + s * 8;
            pAh[p] = *reinterpret_cast<const uint4*>(Ahi + src);
            pAl[p] = *reinterpret_cast<const uint4*>(Alo + src);
        }
    };
    auto stA = [&]() {
#pragma unroll
        for (int p = 0; p < CA; p++) {
            const int id = tid + p * 256;
            const int row = id >> 2, s = id & 3;
            const int dst = row * 64 + ((s ^ ((row >> 1) & 3)) << 4);
            *reinterpret_cast<uint4*>(sAh + dst) = pAh[p];
            *reinterpret_cast<uint4*>(sAl + dst) = pAl[p];
        }
    };

    f32x4 acc[4][4];
#pragma unroll
    for (int m = 0; m < 4; m++)
#pragma unroll
        for (int n = 0; n < 4; n++)
#pragma unroll
            for (int r = 0; r < 4; r++) acc[m][n][r] = 0.f;

    ldgA(0);
    stA();
    __syncthreads();

    for (int t = 0; t < T; t++) {
        bf16x8 Ah[4], Al[4], Bh[4], Bl[4];
#pragma unroll
        for (int m = 0; m < 4; m++) {
            const int row = wr * 64 + m * 16 + ln15;
            const int ab = row * 64 + ((lg ^ m0A) << 4);
            Ah[m] = *reinterpret_cast<const bf16x8*>(sAh + ab);
            Al[m] = *reinterpret_cast<const bf16x8*>(sAl + ab);
        }
#pragma unroll
        for (int n = 0; n < 4; n++) {
            const int row = wc * 64 + n * 16 + ln15;
            const int bb = row * (KD * 2) + ((t ^ m1B) * 64) + ((lg ^ m0B) << 4);
            Bh[n] = *reinterpret_cast<const bf16x8*>(sBh + bb);
            Bl[n] = *reinterpret_cast<const bf16x8*>(sBl + bb);
        }
        __syncthreads();                // frags in regs; A buffer free to overwrite
        if (t + 1 < T) ldgA(t + 1);     // issue loads; latency hides under MFMA
#pragma unroll
        for (int n = 0; n < 4; n++)
#pragma unroll
            for (int m = 0; m < 4; m++) {
                acc[m][n] = __builtin_amdgcn_mfma_f32_16x16x32_bf16(Ah[m], Bh[n], acc[m][n], 0, 0, 0);
                acc[m][n] = __builtin_amdgcn_mfma_f32_16x16x32_bf16(Ah[m], Bl[n], acc[m][n], 0, 0, 0);
                acc[m][n] = __builtin_amdgcn_mfma_f32_16x16x32_bf16(Al[m], Bh[n], acc[m][n], 0, 0, 0);
            }
        if (t + 1 < T) { stA(); __syncthreads(); }  // vmcnt wait lands at stA
    }

#pragma unroll
    for (int m = 0; m < 4; m++) {
        const int l = lB + wr * 64 + m * 16 + lg * 4;
#pragma unroll
        for (int n = 0; n < 4; n++) {
            const int o = oB + wc * 64 + n * 16 + ln15;
            if constexpr (MODE == 4) {
                float4 r4 = {acc[m][n][0], acc[m][n][1], acc[m][n][2], acc[m][n][3]};
                *reinterpret_cast<float4*>(&Yf[((size_t)b * ON + o) * L_ + l]) = r4;
            } else {
                float bv = bias[o];
#pragma unroll
                for (int r = 0; r < 4; r++) {
                    size_t yi = ((size_t)b * L_ + l + r) * ON + o;
                    float a = acc[m][n][r] + bv;
                    if constexpr (MODE == 1) {
                        float sxy = bf2f((ushort)Ahi[yi]) + bf2f((ushort)Alo[yi]);
                        a = 0.5f * a * (1.f + erff(a * 0.70710678118654752f)) * sxy;
                    }
                    if constexpr (MODE == 3) a += E0[yi];
                    ushort h = f2bf(a);
                    ushort g = f2bf(a - bf2f(h));
                    Yhi[yi] = (short)h;
                    Ylo[yi] = (short)g;
                }
            }
        }
    }
}

// ---------------------------------------------------------------------------
// Depthwise 3x3 SAME conv, register-rolling, fused q/k sum & sumsq reduction
// ---------------------------------------------------------------------------
__global__ __launch_bounds__(256) void dwconv_k(const float* __restrict__ in,
    const float* __restrict__ wdw, float* __restrict__ outp,
    float* __restrict__ sumq, float* __restrict__ sumk,
    float* __restrict__ ssq, float* __restrict__ ssk)
{
    const int ch = blockIdx.x, b = blockIdx.y;
    const int tid = threadIdx.x;
    const int tx = tid & 31, band = tid >> 5;
    const int x0 = tx * 4;
    const int y0 = band * 16;
    const size_t base = ((size_t)b * O3_ + ch) * L_;
    const float* wp = wdw + ch * 9;
    float w0 = wp[0], w1 = wp[1], w2 = wp[2], w3 = wp[3], w4 = wp[4],
          w5 = wp[5], w6 = wp[6], w7 = wp[7], w8 = wp[8];

    float s1 = 0.f, s2 = 0.f;
    float b0[6], b1[6], b2[6];

    auto loadrow = [&](int gy, float* r) {
        if ((unsigned)gy < (unsigned)H_) {
            const float* rp = in + base + (size_t)gy * W_;
            float4 m = *reinterpret_cast<const float4*>(rp + x0);
            r[0] = (x0 > 0) ? rp[x0 - 1] : 0.f;
            r[1] = m.x; r[2] = m.y; r[3] = m.z; r[4] = m.w;
            r[5] = (x0 < W_ - 4) ? rp[x0 + 4] : 0.f;
        } else {
            r[0] = r[1] = r[2] = r[3] = r[4] = r[5] = 0.f;
        }
    };
    auto conv3 = [&](const float* ra, const float* rb, const float* rc, int yy) {
        float o0 = ra[0]*w0 + ra[1]*w1 + ra[2]*w2 + rb[0]*w3 + rb[1]*w4 + rb[2]*w5 + rc[0]*w6 + rc[1]*w7 + rc[2]*w8;
        float o1 = ra[1]*w0 + ra[2]*w1 + ra[3]*w2 + rb[1]*w3 + rb[2]*w4 + rb[3]*w5 + rc[1]*w6 + rc[2]*w7 + rc[3]*w8;
        float o2 = ra[2]*w0 + ra[3]*w1 + ra[4]*w2 + rb[2]*w3 + rb[3]*w4 + rb[4]*w5 + rc[2]*w6 + rc[3]*w7 + rc[4]*w8;
        float o3 = ra[3]*w0 + ra[4]*w1 + ra[5]*w2 + rb[3]*w3 + rb[4]*w4 + rb[5]*w5 + rc[3]*w6 + rc[4]*w7 + rc[5]*w8;
        float4 o4 = {o0, o1, o2, o3};
        *reinterpret_cast<float4*>(&outp[base + (size_t)(y0 + yy) * W_ + x0]) = o4;
        s1 += (o0 + o1) + (o2 + o3);
        s2 += o0*o0 + o1*o1 + o2*o2 + o3*o3;
    };

    loadrow(y0 - 1, b0);
    loadrow(y0,     b1);
#pragma unroll
    for (int y3 = 0; y3 < 15; y3 += 3) {
        loadrow(y0 + y3 + 1, b2); conv3(b0, b1, b2, y3);
        loadrow(y0 + y3 + 2, b0); conv3(b1, b2, b0, y3 + 1);
        loadrow(y0 + y3 + 3, b1); conv3(b2, b0, b1, y3 + 2);
    }
    loadrow(y0 + 16, b2); conv3(b0, b1, b2, 15);

    __shared__ float r1[256], r2[256];
    if (ch < 256) {
        r1[tid] = s1; r2[tid] = s2;
        __syncthreads();
        for (int st = 128; st > 0; st >>= 1) {
            if (tid < st) { r1[tid] += r1[tid + st]; r2[tid] += r2[tid + st]; }
            __syncthreads();
        }
        if (tid == 0) {
            if (ch < 128) { sumq[b * 128 + ch] = r1[0]; ssq[b * 128 + ch] = r2[0]; }
            else          { sumk[b * 128 + ch - 128] = r1[0]; ssk[b * 128 + ch - 128] = r2[0]; }
        }
    }
}

// combine: channel means (double) -> stable rank; rq,rk; gm
__global__ void combine_k(const float* __restrict__ sumq, const float* __restrict__ sumk,
    const float* __restrict__ ssq, const float* __restrict__ ssk,
    int* __restrict__ idxp, float* __restrict__ rqc, float* __restrict__ rkc,
    float* __restrict__ gm)
{
    const int t = threadIdx.x; // 128
    __shared__ double cms[128];
    double s = 0.0;
    for (int b = 0; b < B_; b++) s += (double)sumq[b * 128 + t];
    cms[t] = s;
    float rqv[B_], rkv[B_];
    for (int b = 0; b < B_; b++) {
        rqv[b] = 1.f / fmaxf(sqrtf(ssq[b * 128 + t]), 1e-12f);
        rkv[b] = 1.f / fmaxf(sqrtf(ssk[b * 128 + t]), 1e-12f);
        rqc[b * 128 + t] = rqv[b];
        rkc[b * 128 + t] = rkv[b];
    }
    __syncthreads();
    const double mv = cms[t];
    int r = 0;
    for (int j = 0; j < 128; j++) {
        double o = cms[j];
        if (o > mv || (o == mv && j < t)) r++;
    }
    idxp[r] = t;
    for (int b = 0; b < B_; b++)
        gm[b * 128 + r] = (rqv[b] * sumq[b * 128 + t] + rkv[b] * sumk[b * 128 + t]) * (1.0f / L_);
}

// ---------------------------------------------------------------------------
// Partial raw scores: S[c][d] = sum_l q[c,l]*k[d,l] over one L-split (per-G)
// ---------------------------------------------------------------------------
template<int G>
__global__ __launch_bounds__(256) void score_k(const float* __restrict__ dw, const int* __restrict__ idxp,
    int start, int gi, float* __restrict__ spart)
{
    constexpr int TS = G / 16;
    const int split = blockIdx.x, b = blockIdx.y;
    const int tid = threadIdx.x, tx = tid & 15, ty = tid >> 4;
    __shared__ float sQ[G][66];
    __shared__ float sK[G][66];
    __shared__ int sc[G];
    if (tid < G) sc[tid] = idxp[start + tid];
    __syncthreads();

    float acc[TS][TS];
#pragma unroll
    for (int i = 0; i < TS; i++)
#pragma unroll
        for (int j = 0; j < TS; j++) acc[i][j] = 0.f;

    const int l0 = split * (L_ / NS_);
    constexpr int LPT = (G * 64) / 256;
    for (int chk = 0; chk < L_ / NS_; chk += 64) {
#pragma unroll
        for (int i = 0; i < LPT; i++) {
            int id = tid + i * 256;
            int row = id >> 6, lc = id & 63;
            size_t base = ((size_t)b * O3_ + sc[row]) * L_ + l0 + chk + lc;
            sQ[row][lc] = dw[base];
            sK[row][lc] = dw[base + (size_t)128 * L_];
        }
        __syncthreads();
#pragma unroll
        for (int kk = 0; kk < 64; kk++) {
            float qv[TS], kv[TS];
#pragma unroll
            for (int j = 0; j < TS; j++) { qv[j] = sQ[ty * TS + j][kk]; kv[j] = sK[tx * TS + j][kk]; }
#pragma unroll
            for (int i = 0; i < TS; i++)
#pragma unroll
                for (int j = 0; j < TS; j++)
                    acc[i][j] = fmaf(qv[i], kv[j], acc[i][j]);
        }
        __syncthreads();
    }
    float* op = spart + (((size_t)(b * 4 + gi)) * NS_ + split) * MAXP_;
#pragma unroll
    for (int i = 0; i < TS; i++)
#pragma unroll
        for (int j = 0; j < TS; j++)
            op[(ty * TS + i) * G + tx * TS + j] = acc[i][j];
}

// reduce partials, scale by rq*rk*temp, softmax rows -> attn
__global__ __launch_bounds__(256) void softmax_k(const float* __restrict__ spart,
    const float* __restrict__ rqc, const float* __restrict__ rkc, const int* __restrict__ idxp,
    const float* __restrict__ temp, float* __restrict__ attn)
{
    const int gi = blockIdx.x, b = blockIdx.y;
    const int g = (gi == 0) ? 16 : (gi == 3 ? 48 : 32);
    const int start = (gi == 0) ? 0 : (gi == 1 ? 16 : (gi == 2 ? 48 : 80));
    __shared__ float S[MAXP_];
    __shared__ int sidx[48];
    if (threadIdx.x < g) sidx[threadIdx.x] = idxp[start + threadIdx.x];
    __syncthreads();
    const float tv = temp[gi];
    for (int p = threadIdx.x; p < g * g; p += 256) {
        float s = 0.f;
        const float* sp = spart + ((size_t)(b * 4 + gi)) * NS_ * MAXP_ + p;
        for (int k = 0; k < NS_; k++) s += sp[(size_t)k * MAXP_];
        int cc = p / g, dd = p - cc * g;
        S[p] = s * rqc[b * 128 + sidx[cc]] * rkc[b * 128 + sidx[dd]] * tv;
    }
    __syncthreads();
    const int wv = threadIdx.x >> 6, lane = threadIdx.x & 63;
    for (int r = wv; r < g; r += 4) {
        float val = (lane < g) ? S[r * g + lane] : -1e30f;
        float mx = val;
        for (int m = 32; m > 0; m >>= 1) mx = fmaxf(mx, __shfl_xor(mx, m));
        float e = (lane < g) ? expf(val - mx) : 0.f;
        float sum = e;
        for (int m = 32; m > 0; m >>= 1) sum += __shfl_xor(sum, m);
        if (lane < g) attn[((size_t)(b * 4 + gi)) * MAXP_ + r * g + lane] = e / sum;
    }
}

// ---------------------------------------------------------------------------
// attn @ v per-G: outallT fp32 [b][l][c]; sxy split hi/lo planes.
// ---------------------------------------------------------------------------
template<int G>
__global__ __launch_bounds__(256) void av3_k(const float* __restrict__ dw, const int* __restrict__ idxp,
    const float* __restrict__ rqc, const float* __restrict__ rkc,
    const float* __restrict__ attn, int start, int gi,
    float* __restrict__ outallT, short* __restrict__ sxyhi, short* __restrict__ sxylo)
{
    constexpr int C4 = G / 4;
    constexpr int GP = G + 1;
    const int b = blockIdx.y;
    const int lB = blockIdx.x * 64;
    const int tid = threadIdx.x;
    __shared__ float sA[G * GP];
    __shared__ float sV[64][GP];
    __shared__ int cv[G];
    __shared__ float rqs[G], rks[G];
    if (tid < G) {
        int c0 = idxp[start + tid];
        cv[tid] = c0;
        rqs[tid] = rqc[b * 128 + c0];
        rks[tid] = rkc[b * 128 + c0];
    }
    for (int p = tid; p < G * G; p += 256) {
        int cc = p / G, dd = p - cc * G;
        sA[cc * GP + dd] = attn[((size_t)(b * 4 + gi)) * MAXP_ + p];
    }
    __syncthreads();
    for (int idx = tid; idx < 64 * G; idx += 256) {
        int l = idx & 63, d = idx >> 6;
        sV[l][d] = dw[((size_t)b * O3_ + 256 + cv[d]) * L_ + lB + l];
    }
    __syncthreads();
    const int strip = tid & 3, l = tid >> 2;
    float acc[C4];
#pragma unroll
    for (int j = 0; j < C4; j++) acc[j] = 0.f;
    for (int d = 0; d < G; d++) {
        float vd = sV[l][d];
#pragma unroll
        for (int j = 0; j < C4; j++)
            acc[j] = fmaf(sA[(strip * C4 + j) * GP + d], vd, acc[j]);
    }
    const size_t ob = ((size_t)b * L_ + lB + l) * C_ + start + strip * C4;
    float sv[C4];
#pragma unroll
    for (int j = 0; j < C4; j++) {
        int c = strip * C4 + j;
        float q = dw[((size_t)b * O3_ + cv[c]) * L_ + lB + l];
        float k = dw[((size_t)b * O3_ + 128 + cv[c]) * L_ + lB + l];
        sv[j] = acc[j] + rqs[c] * q + rks[c] * k;
    }
#pragma unroll
    for (int j = 0; j < C4; j += 4) {
        float4 o4 = {acc[j], acc[j + 1], acc[j + 2], acc[j + 3]};
        *reinterpret_cast<float4*>(&outallT[ob + j]) = o4;
    }
#pragma unroll
    for (int j = 0; j < C4; j += 2) {
        ushort h0 = f2bf(sv[j]), h1 = f2bf(sv[j + 1]);
        ushort g0 = f2bf(sv[j] - bf2f(h0)), g1 = f2bf(sv[j + 1] - bf2f(h1));
        *reinterpret_cast<uint*>(&sxyhi[ob + j]) = (uint)h0 | ((uint)h1 << 16);
        *reinterpret_cast<uint*>(&sxylo[ob + j]) = (uint)g0 | ((uint)g1 << 16);
    }
}

// qv_cache = 0.9 * mean of tiled group means, broadcast over spatial
__global__ __launch_bounds__(256) void qvc_k(const float* __restrict__ gm, float* __restrict__ outq)
{
    const int cpos = blockIdx.x, b = blockIdx.y;
    const float* g = gm + b * 128;
    float v = g[cpos & 15] + g[16 + (cpos & 31)] + g[48 + (cpos & 31)];
    if (cpos < 96) v += g[80 + (cpos % 48)];
    v *= 0.225f; // 0.9 * (sum/4)
    float4 vv = {v, v, v, v};
    float4* op = reinterpret_cast<float4*>(outq + ((size_t)b * C_ + cpos) * L_);
    for (int i = threadIdx.x; i < L_ / 4; i += 256) op[i] = vv;
}

// ---------------------------------------------------------------------------
extern "C" void kernel_launch(void* const* d_in, const int* in_sizes, int n_in,
                              void* d_out, int out_size, void* d_ws, size_t ws_size,
                              hipStream_t stream)
{
    const float* x     = (const float*)d_in[0];
    const float* temp  = (const float*)d_in[1];
    const float* wqkv  = (const float*)d_in[2];
    const float* wdw   = (const float*)d_in[3];
    const float* wproj = (const float*)d_in[4];
    const float* wgate = (const float*)d_in[5];
    const float* bgate = (const float*)d_in[6];
    const float* wdown = (const float*)d_in[7];
    const float* bdown = (const float*)d_in[8];
    const float* wup   = (const float*)d_in[9];
    const float* bup   = (const float*)d_in[10];
    float* out = (float*)d_out;
    float* ws  = (float*)d_ws;

    // --- ws layout ---
    float* qkvCL = ws;                          // [b][384][L] fp32  [0, 50331648)
    float* dwCL  = ws + 50331648ull;            // [b][384][L] fp32  [50331648, 100663296)
    short* xThi  = (short*)(ws + 50331648ull);  // xT planes: dead before dwconv writes
    short* xTlo  = xThi + 16777216ull;
    float* outallT = ws;                        // fp32 [b][L][128]   [0, 16777216)
    short* sxyhi   = (short*)(ws + 16777216ull);
    short* sxylo   = sxyhi + 16777216ull;
    short* gatedhi = (short*)(ws + 33554432ull);
    short* gatedlo = gatedhi + 16777216ull;
    short* mod1hi  = (short*)(ws + 16777216ull);
    short* mod1lo  = mod1hi + 8388608ull;
    short* out2hi  = (short*)(ws + 33554432ull);
    short* out2lo  = out2hi + 16777216ull;
    // wproj planes: created after up, in the then-dead mod1 region tail
    short* wprojh  = (short*)(ws + 25165824ull);
    short* wprojl  = wprojh + 16384ull;

    // --- d_out layout (first half scratch until proj; second half qv_cache) ---
    float* spart = out;                         // [0, 4718592)
    float* attn  = out + 4718592ull;
    float* sumq  = out + 4800000ull;
    float* sumk  = out + 4801024ull;
    float* ssq   = out + 4802048ull;
    float* ssk   = out + 4803072ull;
    float* rqc   = out + 4804096ull;
    float* rkc   = out + 4805120ull;
    float* gm    = out + 4806144ull;
    int*   idxp  = (int*)(out + 4807168ull);
    // weight hi/lo planes (dead region until proj overwrites; consumed before)
    short* wqkvh = (short*)(out + 4900000ull);
    short* wqkvl = (short*)(out + 4924576ull);
    short* wgateh= (short*)(out + 4949152ull);
    short* wgatel= (short*)(out + 4957344ull);
    short* wdownh= (short*)(out + 4965536ull);
    short* wdownl= (short*)(out + 4969632ull);
    short* wuph  = (short*)(out + 4973728ull);
    short* wupl  = (short*)(out + 4977824ull);

    // 0. weight pre-split (qkv, gate, down, up)
    wsplit_k<<<dim3(192, 4), 256, 0, stream>>>(wqkv, wgate, wdown, wup,
        wqkvh, wqkvl, wgateh, wgatel, wdownh, wdownl, wuph, wupl);
    // 1. transpose+split x
    transp_k<<<dim3(512, 8), 256, 0, stream>>>(x, xThi, xTlo);
    // 2. qkv GEMM -> qkvCL fp32 [b][384][l]
    mgemm_k<128, 128, 4><<<dim3(3, 128, 8), 256, 0, stream>>>(
        wqkvh, wqkvl, nullptr, xThi, xTlo, nullptr, qkvCL, nullptr, nullptr);
    // 3. depthwise 3x3 + fused q/k sums
    dwconv_k<<<dim3(384, 8), 256, 0, stream>>>(qkvCL, wdw, dwCL, sumq, sumk, ssq, ssk);
    // 4. combine: rank + norms + gm
    combine_k<<<1, 128, 0, stream>>>(sumq, sumk, ssq, ssk, idxp, rqc, rkc, gm);
    // 5. attention scores (per-G launches)
    score_k<16><<<dim3(NS_, 8), 256, 0, stream>>>(dwCL, idxp, 0, 0, spart);
    score_k<32><<<dim3(NS_, 8), 256, 0, stream>>>(dwCL, idxp, 16, 1, spart);
    score_k<32><<<dim3(NS_, 8), 256, 0, stream>>>(dwCL, idxp, 48, 2, spart);
    score_k<48><<<dim3(NS_, 8), 256, 0, stream>>>(dwCL, idxp, 80, 3, spart);
    // 6. reduce + softmax
    softmax_k<<<dim3(4, 8), 256, 0, stream>>>(spart, rqc, rkc, idxp, temp, attn);
    // 7. attn @ v (per-G launches) -> outallT fp32 + sxy hi/lo planes
    av3_k<16><<<dim3(256, 8), 256, 0, stream>>>(dwCL, idxp, rqc, rkc, attn, 0, 0, outallT, sxyhi, sxylo);
    av3_k<32><<<dim3(256, 8), 256, 0, stream>>>(dwCL, idxp, rqc, rkc, attn, 16, 1, outallT, sxyhi, sxylo);
    av3_k<32><<<dim3(256, 8), 256, 0, stream>>>(dwCL, idxp, rqc, rkc, attn, 48, 2, outallT, sxyhi, sxylo);
    av3_k<48><<<dim3(256, 8), 256, 0, stream>>>(dwCL, idxp, rqc, rkc, attn, 80, 3, outallT, sxyhi, sxylo);
    // 8. gate GEMM (+gelu * sxy)
    mgemm_k<128, 128, 1><<<dim3(1, 128, 8), 256, 0, stream>>>(
        wgateh, wgatel, bgate, sxyhi, sxylo, nullptr, nullptr, gatedhi, gatedlo);
    // 9. qv_cache
    qvc_k<<<dim3(128, 8), 256, 0, stream>>>(gm, out + 16777216ull);
    // 10. down GEMM
    mgemm_k<128, 64, 2><<<dim3(1, 64, 8), 256, 0, stream>>>(
        wdownh, wdownl, bdown, gatedhi, gatedlo, nullptr, nullptr, mod1hi, mod1lo);
    // 11. up GEMM + residual
    mgemm_k<64, 128, 3><<<dim3(1, 128, 8), 256, 0, stream>>>(
        wuph, wupl, bup, mod1hi, mod1lo, outallT, nullptr, out2hi, out2lo);
    // 12. wproj pre-split (mod1 region is dead now)
    wsplit1_k<<<64, 256, 0, stream>>>(wproj, wprojh, wprojl, 16384);
    // 13. proj GEMM -> final output fp32 [b][128][l]
    mgemm_k<128, 128, 4><<<dim3(1, 128, 8), 256, 0, stream>>>(
        wprojh, wprojl, nullptr, out2hi, out2lo, nullptr, out, nullptr, nullptr);
}

// Round 12
// 721.576 us; speedup vs baseline: 1.0784x; 1.0618x over previous
//
#include <hip/hip_runtime.h>
#include <math.h>

#define B_ 8
#define C_ 128
#define O3_ 384
#define H_ 128
#define W_ 128
#define L_ 16384
#define NS_ 64
#define MAXP_ 2304

typedef float f32x4 __attribute__((ext_vector_type(4)));
typedef short bf16x8 __attribute__((ext_vector_type(8)));

static __device__ __forceinline__ ushort f2bf(float f) {
    uint u = __float_as_uint(f);
    u += 0x7fffu + ((u >> 16) & 1u);
    return (ushort)(u >> 16);
}
static __device__ __forceinline__ float bf2f(ushort h) {
    return __uint_as_float(((uint)h) << 16);
}

// ---------------------------------------------------------------------------
// Weight pre-split: fp32 -> hi/lo bf16 planes
// ---------------------------------------------------------------------------
__global__ __launch_bounds__(256) void wsplit_k(
    const float* __restrict__ wa, const float* __restrict__ wb,
    const float* __restrict__ wc, const float* __restrict__ wd,
    short* __restrict__ ha, short* __restrict__ la,
    short* __restrict__ hb, short* __restrict__ lb,
    short* __restrict__ hc, short* __restrict__ lc,
    short* __restrict__ hd, short* __restrict__ ld)
{
    const int sel = blockIdx.y;
    const float* w = sel == 0 ? wa : (sel == 1 ? wb : (sel == 2 ? wc : wd));
    short* ph = sel == 0 ? ha : (sel == 1 ? hb : (sel == 2 ? hc : hd));
    short* pl = sel == 0 ? la : (sel == 1 ? lb : (sel == 2 ? lc : ld));
    const int n = sel == 0 ? 49152 : (sel == 1 ? 16384 : 8192);
    const int i = blockIdx.x * 256 + threadIdx.x;
    if (i < n) {
        float v = w[i];
        ushort h = f2bf(v);
        ph[i] = (short)h;
        pl[i] = (short)f2bf(v - bf2f(h));
    }
}

__global__ __launch_bounds__(256) void wsplit1_k(const float* __restrict__ w,
    short* __restrict__ ph, short* __restrict__ pl, int n)
{
    const int i = blockIdx.x * 256 + threadIdx.x;
    if (i < n) {
        float v = w[i];
        ushort h = f2bf(v);
        ph[i] = (short)h;
        pl[i] = (short)f2bf(v - bf2f(h));
    }
}

// ---------------------------------------------------------------------------
// Transpose+split: x [b][128c][L] fp32 -> xThi/xTlo [b][L][128c] bf16 planes
// ---------------------------------------------------------------------------
__global__ __launch_bounds__(256) void transp_k(const float* __restrict__ x,
    short* __restrict__ xhi, short* __restrict__ xlo)
{
    __shared__ float t[128][33];
    const int b = blockIdx.y;
    const int l0 = blockIdx.x * 32;
    const int tid = threadIdx.x;
    {
        const int c = tid >> 1, half = tid & 1;
        const float* src = x + ((size_t)b * C_ + c) * L_ + l0 + half * 16;
#pragma unroll
        for (int u = 0; u < 4; u++) {
            float4 v = *reinterpret_cast<const float4*>(src + u * 4);
            t[c][half * 16 + u * 4 + 0] = v.x;
            t[c][half * 16 + u * 4 + 1] = v.y;
            t[c][half * 16 + u * 4 + 2] = v.z;
            t[c][half * 16 + u * 4 + 3] = v.w;
        }
    }
    __syncthreads();
    {
        const int l = tid >> 3, strip = tid & 7;
        uint hi[8], lo[8];
#pragma unroll
        for (int i = 0; i < 8; i++) {
            float a0 = t[strip * 16 + 2 * i][l], a1 = t[strip * 16 + 2 * i + 1][l];
            ushort h0 = f2bf(a0), h1 = f2bf(a1);
            ushort g0 = f2bf(a0 - bf2f(h0)), g1 = f2bf(a1 - bf2f(h1));
            hi[i] = (uint)h0 | ((uint)h1 << 16);
            lo[i] = (uint)g0 | ((uint)g1 << 16);
        }
        size_t ob = ((size_t)b * L_ + l0 + l) * C_ + strip * 16;
        uint4* ph = reinterpret_cast<uint4*>(xhi + ob);
        uint4* pl = reinterpret_cast<uint4*>(xlo + ob);
        ph[0] = *reinterpret_cast<uint4*>(&hi[0]);
        ph[1] = *reinterpret_cast<uint4*>(&hi[4]);
        pl[0] = *reinterpret_cast<uint4*>(&lo[0]);
        pl[1] = *reinterpret_cast<uint4*>(&lo[4]);
    }
}

// ---------------------------------------------------------------------------
// NT MFMA GEMM (bf16x3). B resident in LDS (staged once, XOR-swizzled,
// read-only -> ZERO barriers in K-loop). A loaded per-lane direct from
// global (coalesced 64B lines), double-buffered in regs, prefetch depth 2.
// MODE 1: y=gelu(acc+bias)*(sxy at yi) -> split [l][o]
// MODE 2: y=acc+bias -> split [l][o]
// MODE 3: y=acc+bias+E0 -> split [l][o]
// MODE 4: plain, fp32 transposed store [o][l]
// ---------------------------------------------------------------------------
template<int KD, int OT, int MODE>
__global__ __launch_bounds__(256) void mgemm_k(
    const short* __restrict__ Whi, const short* __restrict__ Wlo,
    const float* __restrict__ bias,
    const short* __restrict__ Ahi, const short* __restrict__ Alo,
    const float* __restrict__ E0,
    float* __restrict__ Yf, short* __restrict__ Yhi, short* __restrict__ Ylo)
{
    constexpr int WC = OT / 64;           // wave-cols
    constexpr int WR = 4 / WC;            // wave-rows
    constexpr int LT = WR * 64;           // l-tile per block
    constexpr int T  = KD / 32;           // k-steps
    constexpr int BBYTES = OT * KD * 2;   // B bytes/plane
    constexpr int CB = (OT * KD) / 2048;  // B 16B-chunks per thread per plane
    __shared__ __align__(16) char sBh[BBYTES];
    __shared__ __align__(16) char sBl[BBYTES];

    const int tid = threadIdx.x;
    const int lane = tid & 63;
    const int wid = tid >> 6;
    const int wr = wid / WC, wc = wid % WC;
    const int oB = blockIdx.x * OT;
    const int lB = blockIdx.y * LT;
    const int ON = gridDim.x * OT;
    const int b  = blockIdx.z;
    const int ln15 = lane & 15, lg = lane >> 4;
    const int m0B = ln15 & 3;                 // B read slot xor
    const int m1B = (ln15 >> 2) & (T - 1);    // B read t xor

    // B: stage once (ldg + swizzled ds_write); verified conflict-free (r10)
#pragma unroll
    for (int p = 0; p < CB; p++) {
        const int id = tid + p * 256;
        const int row = id / (KD / 8), cs = id % (KD / 8);
        const int tt = cs >> 2, ks = cs & 3;
        const size_t src = (size_t)(oB + row) * KD + cs * 8;
        const int dst = row * (KD * 2) + ((tt ^ ((row >> 2) & (T - 1))) * 64)
                      + ((ks ^ (row & 3)) << 4);
        *reinterpret_cast<uint4*>(sBh + dst) = *reinterpret_cast<const uint4*>(Whi + src);
        *reinterpret_cast<uint4*>(sBl + dst) = *reinterpret_cast<const uint4*>(Wlo + src);
    }

    f32x4 acc[4][4];
#pragma unroll
    for (int m = 0; m < 4; m++)
#pragma unroll
        for (int n = 0; n < 4; n++)
#pragma unroll
            for (int r = 0; r < 4; r++) acc[m][n][r] = 0.f;

    // per-lane A addresses: 16 rows x 64B fully-utilized lines per load group
    const size_t arow = ((size_t)b * L_ + lB + wr * 64 + ln15) * KD + lg * 8;

    bf16x8 A0h[4], A0l[4], A1h[4], A1l[4];
    auto ldA = [&](bf16x8* Ah, bf16x8* Al, int t) {
#pragma unroll
        for (int m = 0; m < 4; m++) {
            const size_t g = arow + (size_t)(m * 16) * KD + t * 32;
            Ah[m] = *reinterpret_cast<const bf16x8*>(Ahi + g);
            Al[m] = *reinterpret_cast<const bf16x8*>(Alo + g);
        }
    };

    ldA(A0h, A0l, 0);
    if (T > 1) ldA(A1h, A1l, 1);
    __syncthreads();   // B staged; the only barrier in the kernel

#pragma unroll
    for (int t = 0; t < T; t++) {
        bf16x8 Bh[4], Bl[4];
#pragma unroll
        for (int n = 0; n < 4; n++) {
            const int row = wc * 64 + n * 16 + ln15;
            const int bb = row * (KD * 2) + ((t ^ m1B) * 64) + ((lg ^ m0B) << 4);
            Bh[n] = *reinterpret_cast<const bf16x8*>(sBh + bb);
            Bl[n] = *reinterpret_cast<const bf16x8*>(sBl + bb);
        }
        const bf16x8* Ah = (t & 1) ? A1h : A0h;
        const bf16x8* Al = (t & 1) ? A1l : A0l;
#pragma unroll
        for (int n = 0; n < 4; n++)
#pragma unroll
            for (int m = 0; m < 4; m++) {
                acc[m][n] = __builtin_amdgcn_mfma_f32_16x16x32_bf16(Ah[m], Bh[n], acc[m][n], 0, 0, 0);
                acc[m][n] = __builtin_amdgcn_mfma_f32_16x16x32_bf16(Ah[m], Bl[n], acc[m][n], 0, 0, 0);
                acc[m][n] = __builtin_amdgcn_mfma_f32_16x16x32_bf16(Al[m], Bh[n], acc[m][n], 0, 0, 0);
            }
        // depth-2 reg prefetch into the buffer just consumed (anti-dep safe)
        if (t + 2 < T) {
            if (t & 1) ldA(A1h, A1l, t + 2);
            else       ldA(A0h, A0l, t + 2);
        }
    }

#pragma unroll
    for (int m = 0; m < 4; m++) {
        const int l = lB + wr * 64 + m * 16 + lg * 4;
#pragma unroll
        for (int n = 0; n < 4; n++) {
            const int o = oB + wc * 64 + n * 16 + ln15;
            if constexpr (MODE == 4) {
                float4 r4 = {acc[m][n][0], acc[m][n][1], acc[m][n][2], acc[m][n][3]};
                *reinterpret_cast<float4*>(&Yf[((size_t)b * ON + o) * L_ + l]) = r4;
            } else {
                float bv = bias[o];
#pragma unroll
                for (int r = 0; r < 4; r++) {
                    size_t yi = ((size_t)b * L_ + l + r) * ON + o;
                    float a = acc[m][n][r] + bv;
                    if constexpr (MODE == 1) {
                        float sxy = bf2f((ushort)Ahi[yi]) + bf2f((ushort)Alo[yi]);
                        a = 0.5f * a * (1.f + erff(a * 0.70710678118654752f)) * sxy;
                    }
                    if constexpr (MODE == 3) a += E0[yi];
                    ushort h = f2bf(a);
                    ushort g = f2bf(a - bf2f(h));
                    Yhi[yi] = (short)h;
                    Ylo[yi] = (short)g;
                }
            }
        }
    }
}

// ---------------------------------------------------------------------------
// Depthwise 3x3 SAME conv, register-rolling, fused q/k sum & sumsq reduction
// ---------------------------------------------------------------------------
__global__ __launch_bounds__(256) void dwconv_k(const float* __restrict__ in,
    const float* __restrict__ wdw, float* __restrict__ outp,
    float* __restrict__ sumq, float* __restrict__ sumk,
    float* __restrict__ ssq, float* __restrict__ ssk)
{
    const int ch = blockIdx.x, b = blockIdx.y;
    const int tid = threadIdx.x;
    const int tx = tid & 31, band = tid >> 5;
    const int x0 = tx * 4;
    const int y0 = band * 16;
    const size_t base = ((size_t)b * O3_ + ch) * L_;
    const float* wp = wdw + ch * 9;
    float w0 = wp[0], w1 = wp[1], w2 = wp[2], w3 = wp[3], w4 = wp[4],
          w5 = wp[5], w6 = wp[6], w7 = wp[7], w8 = wp[8];

    float s1 = 0.f, s2 = 0.f;
    float b0[6], b1[6], b2[6];

    auto loadrow = [&](int gy, float* r) {
        if ((unsigned)gy < (unsigned)H_) {
            const float* rp = in + base + (size_t)gy * W_;
            float4 m = *reinterpret_cast<const float4*>(rp + x0);
            r[0] = (x0 > 0) ? rp[x0 - 1] : 0.f;
            r[1] = m.x; r[2] = m.y; r[3] = m.z; r[4] = m.w;
            r[5] = (x0 < W_ - 4) ? rp[x0 + 4] : 0.f;
        } else {
            r[0] = r[1] = r[2] = r[3] = r[4] = r[5] = 0.f;
        }
    };
    auto conv3 = [&](const float* ra, const float* rb, const float* rc, int yy) {
        float o0 = ra[0]*w0 + ra[1]*w1 + ra[2]*w2 + rb[0]*w3 + rb[1]*w4 + rb[2]*w5 + rc[0]*w6 + rc[1]*w7 + rc[2]*w8;
        float o1 = ra[1]*w0 + ra[2]*w1 + ra[3]*w2 + rb[1]*w3 + rb[2]*w4 + rb[3]*w5 + rc[1]*w6 + rc[2]*w7 + rc[3]*w8;
        float o2 = ra[2]*w0 + ra[3]*w1 + ra[4]*w2 + rb[2]*w3 + rb[3]*w4 + rb[4]*w5 + rc[2]*w6 + rc[3]*w7 + rc[4]*w8;
        float o3 = ra[3]*w0 + ra[4]*w1 + ra[5]*w2 + rb[3]*w3 + rb[4]*w4 + rb[5]*w5 + rc[3]*w6 + rc[4]*w7 + rc[5]*w8;
        float4 o4 = {o0, o1, o2, o3};
        *reinterpret_cast<float4*>(&outp[base + (size_t)(y0 + yy) * W_ + x0]) = o4;
        s1 += (o0 + o1) + (o2 + o3);
        s2 += o0*o0 + o1*o1 + o2*o2 + o3*o3;
    };

    loadrow(y0 - 1, b0);
    loadrow(y0,     b1);
#pragma unroll
    for (int y3 = 0; y3 < 15; y3 += 3) {
        loadrow(y0 + y3 + 1, b2); conv3(b0, b1, b2, y3);
        loadrow(y0 + y3 + 2, b0); conv3(b1, b2, b0, y3 + 1);
        loadrow(y0 + y3 + 3, b1); conv3(b2, b0, b1, y3 + 2);
    }
    loadrow(y0 + 16, b2); conv3(b0, b1, b2, 15);

    __shared__ float r1[256], r2[256];
    if (ch < 256) {
        r1[tid] = s1; r2[tid] = s2;
        __syncthreads();
        for (int st = 128; st > 0; st >>= 1) {
            if (tid < st) { r1[tid] += r1[tid + st]; r2[tid] += r2[tid + st]; }
            __syncthreads();
        }
        if (tid == 0) {
            if (ch < 128) { sumq[b * 128 + ch] = r1[0]; ssq[b * 128 + ch] = r2[0]; }
            else          { sumk[b * 128 + ch - 128] = r1[0]; ssk[b * 128 + ch - 128] = r2[0]; }
        }
    }
}

// combine: channel means (double) -> stable rank; rq,rk; gm
__global__ void combine_k(const float* __restrict__ sumq, const float* __restrict__ sumk,
    const float* __restrict__ ssq, const float* __restrict__ ssk,
    int* __restrict__ idxp, float* __restrict__ rqc, float* __restrict__ rkc,
    float* __restrict__ gm)
{
    const int t = threadIdx.x; // 128
    __shared__ double cms[128];
    double s = 0.0;
    for (int b = 0; b < B_; b++) s += (double)sumq[b * 128 + t];
    cms[t] = s;
    float rqv[B_], rkv[B_];
    for (int b = 0; b < B_; b++) {
        rqv[b] = 1.f / fmaxf(sqrtf(ssq[b * 128 + t]), 1e-12f);
        rkv[b] = 1.f / fmaxf(sqrtf(ssk[b * 128 + t]), 1e-12f);
        rqc[b * 128 + t] = rqv[b];
        rkc[b * 128 + t] = rkv[b];
    }
    __syncthreads();
    const double mv = cms[t];
    int r = 0;
    for (int j = 0; j < 128; j++) {
        double o = cms[j];
        if (o > mv || (o == mv && j < t)) r++;
    }
    idxp[r] = t;
    for (int b = 0; b < B_; b++)
        gm[b * 128 + r] = (rqv[b] * sumq[b * 128 + t] + rkv[b] * sumk[b * 128 + t]) * (1.0f / L_);
}

// ---------------------------------------------------------------------------
// Partial raw scores: S[c][d] = sum_l q[c,l]*k[d,l] over one L-split (per-G)
// ---------------------------------------------------------------------------
template<int G>
__global__ __launch_bounds__(256) void score_k(const float* __restrict__ dw, const int* __restrict__ idxp,
    int start, int gi, float* __restrict__ spart)
{
    constexpr int TS = G / 16;
    const int split = blockIdx.x, b = blockIdx.y;
    const int tid = threadIdx.x, tx = tid & 15, ty = tid >> 4;
    __shared__ float sQ[G][66];
    __shared__ float sK[G][66];
    __shared__ int sc[G];
    if (tid < G) sc[tid] = idxp[start + tid];
    __syncthreads();

    float acc[TS][TS];
#pragma unroll
    for (int i = 0; i < TS; i++)
#pragma unroll
        for (int j = 0; j < TS; j++) acc[i][j] = 0.f;

    const int l0 = split * (L_ / NS_);
    constexpr int LPT = (G * 64) / 256;
    for (int chk = 0; chk < L_ / NS_; chk += 64) {
#pragma unroll
        for (int i = 0; i < LPT; i++) {
            int id = tid + i * 256;
            int row = id >> 6, lc = id & 63;
            size_t base = ((size_t)b * O3_ + sc[row]) * L_ + l0 + chk + lc;
            sQ[row][lc] = dw[base];
            sK[row][lc] = dw[base + (size_t)128 * L_];
        }
        __syncthreads();
#pragma unroll
        for (int kk = 0; kk < 64; kk++) {
            float qv[TS], kv[TS];
#pragma unroll
            for (int j = 0; j < TS; j++) { qv[j] = sQ[ty * TS + j][kk]; kv[j] = sK[tx * TS + j][kk]; }
#pragma unroll
            for (int i = 0; i < TS; i++)
#pragma unroll
                for (int j = 0; j < TS; j++)
                    acc[i][j] = fmaf(qv[i], kv[j], acc[i][j]);
        }
        __syncthreads();
    }
    float* op = spart + (((size_t)(b * 4 + gi)) * NS_ + split) * MAXP_;
#pragma unroll
    for (int i = 0; i < TS; i++)
#pragma unroll
        for (int j = 0; j < TS; j++)
            op[(ty * TS + i) * G + tx * TS + j] = acc[i][j];
}

// reduce partials, scale by rq*rk*temp, softmax rows -> attn
__global__ __launch_bounds__(256) void softmax_k(const float* __restrict__ spart,
    const float* __restrict__ rqc, const float* __restrict__ rkc, const int* __restrict__ idxp,
    const float* __restrict__ temp, float* __restrict__ attn)
{
    const int gi = blockIdx.x, b = blockIdx.y;
    const int g = (gi == 0) ? 16 : (gi == 3 ? 48 : 32);
    const int start = (gi == 0) ? 0 : (gi == 1 ? 16 : (gi == 2 ? 48 : 80));
    __shared__ float S[MAXP_];
    __shared__ int sidx[48];
    if (threadIdx.x < g) sidx[threadIdx.x] = idxp[start + threadIdx.x];
    __syncthreads();
    const float tv = temp[gi];
    for (int p = threadIdx.x; p < g * g; p += 256) {
        float s = 0.f;
        const float* sp = spart + ((size_t)(b * 4 + gi)) * NS_ * MAXP_ + p;
        for (int k = 0; k < NS_; k++) s += sp[(size_t)k * MAXP_];
        int cc = p / g, dd = p - cc * g;
        S[p] = s * rqc[b * 128 + sidx[cc]] * rkc[b * 128 + sidx[dd]] * tv;
    }
    __syncthreads();
    const int wv = threadIdx.x >> 6, lane = threadIdx.x & 63;
    for (int r = wv; r < g; r += 4) {
        float val = (lane < g) ? S[r * g + lane] : -1e30f;
        float mx = val;
        for (int m = 32; m > 0; m >>= 1) mx = fmaxf(mx, __shfl_xor(mx, m));
        float e = (lane < g) ? expf(val - mx) : 0.f;
        float sum = e;
        for (int m = 32; m > 0; m >>= 1) sum += __shfl_xor(sum, m);
        if (lane < g) attn[((size_t)(b * 4 + gi)) * MAXP_ + r * g + lane] = e / sum;
    }
}

// ---------------------------------------------------------------------------
// attn @ v per-G: outallT fp32 [b][l][c]; sxy split hi/lo planes.
// ---------------------------------------------------------------------------
template<int G>
__global__ __launch_bounds__(256) void av3_k(const float* __restrict__ dw, const int* __restrict__ idxp,
    const float* __restrict__ rqc, const float* __restrict__ rkc,
    const float* __restrict__ attn, int start, int gi,
    float* __restrict__ outallT, short* __restrict__ sxyhi, short* __restrict__ sxylo)
{
    constexpr int C4 = G / 4;
    constexpr int GP = G + 1;
    const int b = blockIdx.y;
    const int lB = blockIdx.x * 64;
    const int tid = threadIdx.x;
    __shared__ float sA[G * GP];
    __shared__ float sV[64][GP];
    __shared__ int cv[G];
    __shared__ float rqs[G], rks[G];
    if (tid < G) {
        int c0 = idxp[start + tid];
        cv[tid] = c0;
        rqs[tid] = rqc[b * 128 + c0];
        rks[tid] = rkc[b * 128 + c0];
    }
    for (int p = tid; p < G * G; p += 256) {
        int cc = p / G, dd = p - cc * G;
        sA[cc * GP + dd] = attn[((size_t)(b * 4 + gi)) * MAXP_ + p];
    }
    __syncthreads();
    for (int idx = tid; idx < 64 * G; idx += 256) {
        int l = idx & 63, d = idx >> 6;
        sV[l][d] = dw[((size_t)b * O3_ + 256 + cv[d]) * L_ + lB + l];
    }
    __syncthreads();
    const int strip = tid & 3, l = tid >> 2;
    float acc[C4];
#pragma unroll
    for (int j = 0; j < C4; j++) acc[j] = 0.f;
    for (int d = 0; d < G; d++) {
        float vd = sV[l][d];
#pragma unroll
        for (int j = 0; j < C4; j++)
            acc[j] = fmaf(sA[(strip * C4 + j) * GP + d], vd, acc[j]);
    }
    const size_t ob = ((size_t)b * L_ + lB + l) * C_ + start + strip * C4;
    float sv[C4];
#pragma unroll
    for (int j = 0; j < C4; j++) {
        int c = strip * C4 + j;
        float q = dw[((size_t)b * O3_ + cv[c]) * L_ + lB + l];
        float k = dw[((size_t)b * O3_ + 128 + cv[c]) * L_ + lB + l];
        sv[j] = acc[j] + rqs[c] * q + rks[c] * k;
    }
#pragma unroll
    for (int j = 0; j < C4; j += 4) {
        float4 o4 = {acc[j], acc[j + 1], acc[j + 2], acc[j + 3]};
        *reinterpret_cast<float4*>(&outallT[ob + j]) = o4;
    }
#pragma unroll
    for (int j = 0; j < C4; j += 2) {
        ushort h0 = f2bf(sv[j]), h1 = f2bf(sv[j + 1]);
        ushort g0 = f2bf(sv[j] - bf2f(h0)), g1 = f2bf(sv[j + 1] - bf2f(h1));
        *reinterpret_cast<uint*>(&sxyhi[ob + j]) = (uint)h0 | ((uint)h1 << 16);
        *reinterpret_cast<uint*>(&sxylo[ob + j]) = (uint)g0 | ((uint)g1 << 16);
    }
}

// qv_cache = 0.9 * mean of tiled group means, broadcast over spatial
__global__ __launch_bounds__(256) void qvc_k(const float* __restrict__ gm, float* __restrict__ outq)
{
    const int cpos = blockIdx.x, b = blockIdx.y;
    const float* g = gm + b * 128;
    float v = g[cpos & 15] + g[16 + (cpos & 31)] + g[48 + (cpos & 31)];
    if (cpos < 96) v += g[80 + (cpos % 48)];
    v *= 0.225f; // 0.9 * (sum/4)
    float4 vv = {v, v, v, v};
    float4* op = reinterpret_cast<float4*>(outq + ((size_t)b * C_ + cpos) * L_);
    for (int i = threadIdx.x; i < L_ / 4; i += 256) op[i] = vv;
}

// ---------------------------------------------------------------------------
extern "C" void kernel_launch(void* const* d_in, const int* in_sizes, int n_in,
                              void* d_out, int out_size, void* d_ws, size_t ws_size,
                              hipStream_t stream)
{
    const float* x     = (const float*)d_in[0];
    const float* temp  = (const float*)d_in[1];
    const float* wqkv  = (const float*)d_in[2];
    const float* wdw   = (const float*)d_in[3];
    const float* wproj = (const float*)d_in[4];
    const float* wgate = (const float*)d_in[5];
    const float* bgate = (const float*)d_in[6];
    const float* wdown = (const float*)d_in[7];
    const float* bdown = (const float*)d_in[8];
    const float* wup   = (const float*)d_in[9];
    const float* bup   = (const float*)d_in[10];
    float* out = (float*)d_out;
    float* ws  = (float*)d_ws;

    // --- ws layout ---
    float* qkvCL = ws;                          // [b][384][L] fp32  [0, 50331648)
    float* dwCL  = ws + 50331648ull;            // [b][384][L] fp32  [50331648, 100663296)
    short* xThi  = (short*)(ws + 50331648ull);  // xT planes: dead before dwconv writes
    short* xTlo  = xThi + 16777216ull;
    float* outallT = ws;                        // fp32 [b][L][128]   [0, 16777216)
    short* sxyhi   = (short*)(ws + 16777216ull);
    short* sxylo   = sxyhi + 16777216ull;
    short* gatedhi = (short*)(ws + 33554432ull);
    short* gatedlo = gatedhi + 16777216ull;
    short* mod1hi  = (short*)(ws + 16777216ull);
    short* mod1lo  = mod1hi + 8388608ull;
    short* out2hi  = (short*)(ws + 33554432ull);
    short* out2lo  = out2hi + 16777216ull;
    // wproj planes: created after up, in the then-dead mod1 region tail
    short* wprojh  = (short*)(ws + 25165824ull);
    short* wprojl  = wprojh + 16384ull;

    // --- d_out layout (first half scratch until proj; second half qv_cache) ---
    float* spart = out;                         // [0, 4718592)
    float* attn  = out + 4718592ull;
    float* sumq  = out + 4800000ull;
    float* sumk  = out + 4801024ull;
    float* ssq   = out + 4802048ull;
    float* ssk   = out + 4803072ull;
    float* rqc   = out + 4804096ull;
    float* rkc   = out + 4805120ull;
    float* gm    = out + 4806144ull;
    int*   idxp  = (int*)(out + 4807168ull);
    // weight hi/lo planes (dead region until proj overwrites; consumed before)
    short* wqkvh = (short*)(out + 4900000ull);
    short* wqkvl = (short*)(out + 4924576ull);
    short* wgateh= (short*)(out + 4949152ull);
    short* wgatel= (short*)(out + 4957344ull);
    short* wdownh= (short*)(out + 4965536ull);
    short* wdownl= (short*)(out + 4969632ull);
    short* wuph  = (short*)(out + 4973728ull);
    short* wupl  = (short*)(out + 4977824ull);

    // 0. weight pre-split (qkv, gate, down, up)
    wsplit_k<<<dim3(192, 4), 256, 0, stream>>>(wqkv, wgate, wdown, wup,
        wqkvh, wqkvl, wgateh, wgatel, wdownh, wdownl, wuph, wupl);
    // 1. transpose+split x
    transp_k<<<dim3(512, 8), 256, 0, stream>>>(x, xThi, xTlo);
    // 2. qkv GEMM -> qkvCL fp32 [b][384][l]
    mgemm_k<128, 128, 4><<<dim3(3, 128, 8), 256, 0, stream>>>(
        wqkvh, wqkvl, nullptr, xThi, xTlo, nullptr, qkvCL, nullptr, nullptr);
    // 3. depthwise 3x3 + fused q/k sums
    dwconv_k<<<dim3(384, 8), 256, 0, stream>>>(qkvCL, wdw, dwCL, sumq, sumk, ssq, ssk);
    // 4. combine: rank + norms + gm
    combine_k<<<1, 128, 0, stream>>>(sumq, sumk, ssq, ssk, idxp, rqc, rkc, gm);
    // 5. attention scores (per-G launches)
    score_k<16><<<dim3(NS_, 8), 256, 0, stream>>>(dwCL, idxp, 0, 0, spart);
    score_k<32><<<dim3(NS_, 8), 256, 0, stream>>>(dwCL, idxp, 16, 1, spart);
    score_k<32><<<dim3(NS_, 8), 256, 0, stream>>>(dwCL, idxp, 48, 2, spart);
    score_k<48><<<dim3(NS_, 8), 256, 0, stream>>>(dwCL, idxp, 80, 3, spart);
    // 6. reduce + softmax
    softmax_k<<<dim3(4, 8), 256, 0, stream>>>(spart, rqc, rkc, idxp, temp, attn);
    // 7. attn @ v (per-G launches) -> outallT fp32 + sxy hi/lo planes
    av3_k<16><<<dim3(256, 8), 256, 0, stream>>>(dwCL, idxp, rqc, rkc, attn, 0, 0, outallT, sxyhi, sxylo);
    av3_k<32><<<dim3(256, 8), 256, 0, stream>>>(dwCL, idxp, rqc, rkc, attn, 16, 1, outallT, sxyhi, sxylo);
    av3_k<32><<<dim3(256, 8), 256, 0, stream>>>(dwCL, idxp, rqc, rkc, attn, 48, 2, outallT, sxyhi, sxylo);
    av3_k<48><<<dim3(256, 8), 256, 0, stream>>>(dwCL, idxp, rqc, rkc, attn, 80, 3, outallT, sxyhi, sxylo);
    // 8. gate GEMM (+gelu * sxy)
    mgemm_k<128, 128, 1><<<dim3(1, 128, 8), 256, 0, stream>>>(
        wgateh, wgatel, bgate, sxyhi, sxylo, nullptr, nullptr, gatedhi, gatedlo);
    // 9. qv_cache
    qvc_k<<<dim3(128, 8), 256, 0, stream>>>(gm, out + 16777216ull);
    // 10. down GEMM
    mgemm_k<128, 64, 2><<<dim3(1, 64, 8), 256, 0, stream>>>(
        wdownh, wdownl, bdown, gatedhi, gatedlo, nullptr, nullptr, mod1hi, mod1lo);
    // 11. up GEMM + residual
    mgemm_k<64, 128, 3><<<dim3(1, 128, 8), 256, 0, stream>>>(
        wuph, wupl, bup, mod1hi, mod1lo, outallT, nullptr, out2hi, out2lo);
    // 12. wproj pre-split (mod1 region is dead now)
    wsplit1_k<<<64, 256, 0, stream>>>(wproj, wprojh, wprojl, 16384);
    // 13. proj GEMM -> final output fp32 [b][128][l]
    mgemm_k<128, 128, 4><<<dim3(1, 128, 8), 256, 0, stream>>>(
        wprojh, wprojl, nullptr, out2hi, out2lo, nullptr, out, nullptr, nullptr);
}